// Round 18
// baseline (233.687 us; speedup 1.0000x reference)
//
#include <hip/hip_runtime.h>
#include <hip/hip_bf16.h>
#include <stdint.h>

#define N_NODES 50000
#define N_EDGES 800000
#define D_H 128
#define D_E 64
#define HID 128

#define MTILE 96
#define SMAX 16
#define N_ETILES ((N_EDGES + MTILE - 1) / MTILE)     // 8334

#define SCAN_B 512
#define N_CHUNKS ((N_NODES + SCAN_B - 1) / SCAN_B)   // 98

typedef __attribute__((ext_vector_type(8))) short bf16x8;
typedef __attribute__((ext_vector_type(4))) short s16x4;
typedef __attribute__((ext_vector_type(4))) float f32x4;
typedef __attribute__((ext_vector_type(4))) int i32x4;

__device__ __forceinline__ unsigned short f2bf(float x) {
    unsigned int u = __float_as_uint(x);
    u += 0x7FFFu + ((u >> 16) & 1u);   // round-to-nearest-even
    return (unsigned short)(u >> 16);
}

__device__ __forceinline__ s16x4 pack4(const f32x4 v) {
    s16x4 o = { (short)f2bf(v[0]), (short)f2bf(v[1]),
                (short)f2bf(v[2]), (short)f2bf(v[3]) };
    return o;
}

__device__ __forceinline__ bf16x8 pack8(const f32x4 a, const f32x4 b) {
    bf16x8 o = { (short)f2bf(a[0]), (short)f2bf(a[1]), (short)f2bf(a[2]), (short)f2bf(a[3]),
                 (short)f2bf(b[0]), (short)f2bf(b[1]), (short)f2bf(b[2]), (short)f2bf(b[3]) };
    return o;
}

// ---------------- zero: gmax (f32) + deg ----------------
#define NG4 (N_NODES * HID / 4)
#define ND4 (N_NODES / 4)
__global__ void zero_ws(float* __restrict__ gmax, int* __restrict__ deg) {
    const int i = blockIdx.x * blockDim.x + threadIdx.x;
    if (i < NG4) {
        ((f32x4*)gmax)[i] = f32x4{0.f, 0.f, 0.f, 0.f};
    } else if (i < NG4 + ND4) {
        ((i32x4*)deg)[i - NG4] = i32x4{0, 0, 0, 0};
    }
}

// ---------------- fused: {Hb,W1t,W2t} convert ++ hist (deg zeroed in prior kernel) ----------------
#define NHB4 (N_NODES * D_H / 4)
#define NW1 (192 * HID)
#define NW2 (256 * HID)
#define CB  ((NHB4 + NW1 + NW2 + 255) / 256)       // 6474 conv blocks
#define HB  ((N_EDGES / 4 + 255) / 256)            // 782 hist blocks
__global__ void conv_hist(const float* __restrict__ H,
                          const float* __restrict__ W1,
                          const float* __restrict__ W2,
                          unsigned short* __restrict__ Hb,
                          unsigned short* __restrict__ W1t,
                          unsigned short* __restrict__ W2t,
                          const int* __restrict__ idx,
                          int* __restrict__ deg, int nConv) {
    const int b = blockIdx.x;
    if (b < nConv) {
        const int i = b * 256 + threadIdx.x;
        if (i < NHB4) {
            ((s16x4*)Hb)[i] = pack4(((const f32x4*)H)[i]);
        } else if (i < NHB4 + NW1) {                 // W1t [128][192] bf16
            const int j = i - NHB4;
            const int n = j / 192, k = j - n * 192;
            W1t[j] = f2bf(W1[k * HID + n]);
        } else if (i < NHB4 + NW1 + NW2) {           // W2t [128][256] bf16
            const int j = i - NHB4 - NW1;
            const int n = j >> 8, k = j & 255;
            W2t[j] = f2bf(W2[k * HID + n]);
        }
    } else {                                         // hist: 4 edges/thread
        const int i = (b - nConv) * 256 + threadIdx.x;
        if (i < N_EDGES / 4) {
            const i32x4 d4 = ((const i32x4*)(idx + N_EDGES))[i];
            atomicAdd(&deg[d4.x], 1);
            atomicAdd(&deg[d4.y], 1);
            atomicAdd(&deg[d4.z], 1);
            atomicAdd(&deg[d4.w], 1);
        }
    }
}

// ---------------- hist standalone (no-aux fallback path) ----------------
__global__ void hist(const int* __restrict__ idx, int* __restrict__ deg) {
    const int i = blockIdx.x * blockDim.x + threadIdx.x;
    if (i < N_EDGES / 4) {
        const i32x4 d4 = ((const i32x4*)(idx + N_EDGES))[i];
        atomicAdd(&deg[d4.x], 1);
        atomicAdd(&deg[d4.y], 1);
        atomicAdd(&deg[d4.z], 1);
        atomicAdd(&deg[d4.w], 1);
    }
}

// ---------------- 3-kernel parallel exclusive scan ----------------
__global__ void scan_a(const int* __restrict__ deg, int* __restrict__ sc,
                       int* __restrict__ totals) {
    __shared__ int s[SCAN_B];
    const int tid = threadIdx.x;
    const int i = blockIdx.x * SCAN_B + tid;
    const int v = (i < N_NODES) ? deg[i] : 0;
    s[tid] = v;
    __syncthreads();
    for (int o = 1; o < SCAN_B; o <<= 1) {
        int t = (tid >= o) ? s[tid - o] : 0;
        __syncthreads();
        s[tid] += t;
        __syncthreads();
    }
    if (i < N_NODES) sc[i] = s[tid] - v;
    if (tid == SCAN_B - 1) totals[blockIdx.x] = s[SCAN_B - 1];
}

__global__ void scan_b(int* __restrict__ totals) {
    __shared__ int s[128];
    const int tid = threadIdx.x;
    const int v = (tid < N_CHUNKS) ? totals[tid] : 0;
    s[tid] = v;
    __syncthreads();
    for (int o = 1; o < 128; o <<= 1) {
        int t = (tid >= o) ? s[tid - o] : 0;
        __syncthreads();
        s[tid] += t;
        __syncthreads();
    }
    if (tid < N_CHUNKS) totals[tid] = s[tid] - v;
}

__global__ void scan_c(const int* __restrict__ sc, const int* __restrict__ totals,
                       int* __restrict__ cursor) {
    const int i = blockIdx.x * SCAN_B + threadIdx.x;
    if (i < N_NODES) cursor[i] = sc[i] + totals[blockIdx.x];
}

// ---------------- scatter: 4 edges/thread, packed 8B store per edge ----------------
__global__ void scatter(const int* __restrict__ idx, int* __restrict__ cursor,
                        unsigned long long* __restrict__ pk8) {
    const int i = blockIdx.x * blockDim.x + threadIdx.x;
    if (i < N_EDGES / 4) {
        const i32x4 s4 = ((const i32x4*)idx)[i];
        const i32x4 d4 = ((const i32x4*)(idx + N_EDGES))[i];
        #pragma unroll
        for (int q = 0; q < 4; ++q) {
            const int e = i * 4 + q;
            const int s = (q == 0) ? s4.x : (q == 1) ? s4.y : (q == 2) ? s4.z : s4.w;
            const int d = (q == 0) ? d4.x : (q == 1) ? d4.y : (q == 2) ? d4.z : d4.w;
            const int p = atomicAdd(&cursor[d], 1);
            pk8[p] = (unsigned long long)(unsigned)e |
                     ((unsigned long long)(unsigned)s << 20) |
                     ((unsigned long long)(unsigned)d << 37);
        }
    }
}

// ---------------- edge MLP: gld_lds H-staging, ymax ALIASED onto sH (R17 proven) ----------------
__global__ __launch_bounds__(256, 4)
void edge_sorted(const float* __restrict__ H,
                 const unsigned short* __restrict__ Hb,
                 const float* __restrict__ Xe,
                 const float* __restrict__ W1,
                 const unsigned short* __restrict__ W1t,
                 const unsigned long long* __restrict__ pk8,
                 float* __restrict__ gmax, int useAux) {
    __shared__ unsigned short sH[MTILE * 128];       // 24.6 KB; ymax aliases this
    __shared__ unsigned short sXe[MTILE][72];        // 13.8 KB (64 + 8 pad)
    __shared__ int rowD[MTILE];
    __shared__ int segNode[SMAX];
    __shared__ int sWaveTot[4];
    __shared__ unsigned char rowG[MTILE];

    float (*ymax)[132] = reinterpret_cast<float(*)[132]>(sH);

    const int tid  = threadIdx.x;
    const int wave = tid >> 6;
    const int lane = tid & 63;
    const int p0   = blockIdx.x * MTILE;

    const int col = lane & 15;
    const int kr0 = (lane >> 4) * 8;

    // --- stage H: async DMA to LDS (useAux) or register path (fallback) ---
    if (useAux) {
        #pragma unroll
        for (int it = 0; it < 6; ++it) {
            const int j   = tid + it * 256;          // < 1536 = 96 rows x 16 chunks
            const int row = j >> 4;
            const int ch  = j & 15;
            int pe = p0 + row; if (pe >= N_EDGES) pe = N_EDGES - 1;
            const int src = (int)((pk8[pe] >> 20) & 0x1FFFFull);
            const int sw  = ch ^ (row & 7);          // source-side swizzle
            unsigned short* lbase = sH + (size_t)(it * 256 + wave * 64) * 8;
            __builtin_amdgcn_global_load_lds(
                (const __attribute__((address_space(1))) void*)(Hb + (size_t)src * D_H + sw * 8),
                (__attribute__((address_space(3))) void*)lbase,
                16, 0, 0);
        }
    } else {
        #pragma unroll
        for (int it = 0; it < 12; ++it) {
            const int j   = tid + it * 256;          // < 3072
            const int row = j >> 5;
            const int q4  = j & 31;
            const int c   = q4 >> 1;
            const int hl  = q4 & 1;
            int pe = p0 + row; if (pe >= N_EDGES) pe = N_EDGES - 1;
            const int src = (int)((pk8[pe] >> 20) & 0x1FFFFull);
            const f32x4 v = *(const f32x4*)(H + (size_t)src * D_H + q4 * 4);
            const int sw  = c ^ (row & 7);
            *(s16x4*)&sH[(size_t)row * 128 + sw * 8 + hl * 4] = pack4(v);
        }
    }
    // --- stage Xe (register path: needs f32->bf16 convert) ---
    #pragma unroll
    for (int it = 0; it < 3; ++it) {
        const int j   = tid + it * 256;              // < 768
        const int row = j >> 3;
        const int c8  = (j & 7) * 8;
        int pe = p0 + row; if (pe >= N_EDGES) pe = N_EDGES - 1;
        const int e = (int)(pk8[pe] & 0xFFFFFull);
        const float* p = Xe + (size_t)e * D_E + c8;
        *(bf16x8*)&sXe[row][c8] = pack8(*(const f32x4*)p, *(const f32x4*)(p + 4));
    }

    // --- B fragments (W1), wave covers cols [wave*32, wave*32+32)
    bf16x8 bfrag[6][2];
    if (useAux) {
        #pragma unroll
        for (int ks = 0; ks < 6; ++ks)
            #pragma unroll
            for (int nf = 0; nf < 2; ++nf) {
                const int n = wave * 32 + nf * 16 + col;
                bfrag[ks][nf] = *(const bf16x8*)&W1t[(size_t)n * 192 + ks * 32 + kr0];
            }
    } else {
        #pragma unroll
        for (int ks = 0; ks < 6; ++ks)
            #pragma unroll
            for (int nf = 0; nf < 2; ++nf) {
                const int n  = wave * 32 + nf * 16 + col;
                const int kb = ks * 32 + kr0;
                bf16x8 b;
                #pragma unroll
                for (int f = 0; f < 8; ++f) b[f] = (short)f2bf(W1[(kb + f) * HID + n]);
                bfrag[ks][nf] = b;
            }
    }

    // --- tile-local segmentation ---
    const int pe0 = p0 + tid;
    const bool inTile = (tid < MTILE);
    const bool valid  = inTile && (pe0 < N_EDGES);
    int d = 0;
    if (inTile) {
        const int pc = valid ? pe0 : (N_EDGES - 1);
        d = (int)(pk8[pc] >> 37);
        rowD[tid] = d;
    }
    int dp = __shfl_up(d, 1);
    if (lane == 0 && inTile && tid > 0) dp = (int)(pk8[pe0 - 1] >> 37);
    const bool flag = valid && (tid == 0 || d != dp);
    const unsigned long long m = __ballot(flag);
    if (lane == 0) sWaveTot[wave] = (int)__popcll(m);
    __syncthreads();                                  // A: gld_lds drained, sWaveTot ready

    const int nSegR = sWaveTot[0] + sWaveTot[1];
    int g = 255;
    if (valid) {
        const unsigned long long le =
            (lane == 63) ? ~0ull : ((1ull << (lane + 1)) - 1);
        g = (int)__popcll(m & le) - 1 + ((wave == 1) ? sWaveTot[0] : 0);
    }
    if (inTile) rowG[tid] = (unsigned char)(valid ? g : 255);
    if (flag && g < SMAX) segNode[g] = d;
    __syncthreads();                                  // B: sH/sXe + rowG + segNode ready

    // --- MFMA: 96 x 192 @ 192 x 32 per wave (swizzled sH read for ks<4)
    f32x4 acc[6][2];
    #pragma unroll
    for (int mm = 0; mm < 6; ++mm) {
        acc[mm][0] = f32x4{0.f, 0.f, 0.f, 0.f};
        acc[mm][1] = f32x4{0.f, 0.f, 0.f, 0.f};
    }
    const int arow = lane & 15;
    const int cgrp = lane >> 4;
    __builtin_amdgcn_s_setprio(1);
    #pragma unroll
    for (int ks = 0; ks < 6; ++ks)
        #pragma unroll
        for (int mm = 0; mm < 6; ++mm) {
            const int r = mm * 16 + arow;
            bf16x8 a;
            if (ks < 4) {
                const int c = ks * 4 + cgrp;
                a = *(const bf16x8*)&sH[(size_t)r * 128 + ((c ^ (r & 7)) << 3)];
            } else {
                a = *(const bf16x8*)&sXe[r][(ks - 4) * 32 + kr0];
            }
            acc[mm][0] = __builtin_amdgcn_mfma_f32_16x16x32_bf16(a, bfrag[ks][0], acc[mm][0], 0, 0, 0);
            acc[mm][1] = __builtin_amdgcn_mfma_f32_16x16x32_bf16(a, bfrag[ks][1], acc[mm][1], 0, 0, 0);
        }
    __builtin_amdgcn_s_setprio(0);
    __syncthreads();                                  // B2: all sH reads done -> sH dead

    for (int i2 = tid; i2 < SMAX * 132; i2 += 256) ((float*)ymax)[i2] = 0.f;
    __syncthreads();                                  // B3: zeros visible

    // --- relu + segmented max into LDS (overflow segs -> direct global atomics)
    const int rb = (lane >> 4) * 4;
    const int cb = wave * 32 + col;
    #pragma unroll
    for (int mm = 0; mm < 6; ++mm) {
        const int r0 = mm * 16 + rb;
        const int g0 = rowG[r0];
        const int g3 = rowG[r0 + 3];
        if (g0 == g3) {
            const float v0 = fmaxf(fmaxf(acc[mm][0][0], acc[mm][0][1]),
                                   fmaxf(acc[mm][0][2], acc[mm][0][3]));
            const float v1 = fmaxf(fmaxf(acc[mm][1][0], acc[mm][1][1]),
                                   fmaxf(acc[mm][1][2], acc[mm][1][3]));
            if (g0 < SMAX) {
                if (v0 > 0.f) atomicMax((int*)&ymax[g0][cb],      __float_as_int(v0));
                if (v1 > 0.f) atomicMax((int*)&ymax[g0][cb + 16], __float_as_int(v1));
            } else if (g0 < 255) {
                float* base = gmax + (size_t)rowD[r0] * HID;
                if (v0 > 0.f) atomicMax((int*)(base + cb),      __float_as_int(v0));
                if (v1 > 0.f) atomicMax((int*)(base + cb + 16), __float_as_int(v1));
            }
        } else {
            #pragma unroll
            for (int r = 0; r < 4; ++r) {
                const int gg = rowG[r0 + r];
                const float v0 = acc[mm][0][r];
                const float v1 = acc[mm][1][r];
                if (gg < SMAX) {
                    if (v0 > 0.f) atomicMax((int*)&ymax[gg][cb],      __float_as_int(v0));
                    if (v1 > 0.f) atomicMax((int*)&ymax[gg][cb + 16], __float_as_int(v1));
                } else if (gg < 255) {
                    float* base = gmax + (size_t)rowD[r0 + r] * HID;
                    if (v0 > 0.f) atomicMax((int*)(base + cb),      __float_as_int(v0));
                    if (v1 > 0.f) atomicMax((int*)(base + cb + 16), __float_as_int(v1));
                }
            }
        }
    }
    __syncthreads();                                  // C: ymax complete

    // --- writeout: interior segments plain store, first/last atomicMax
    const int nS = (nSegR < SMAX) ? nSegR : SMAX;
    for (int i2 = tid; i2 < nS * 128; i2 += 256) {
        const int sg = i2 >> 7;
        const int c  = i2 & 127;
        const float v = ymax[sg][c];
        float* dst = gmax + (size_t)segNode[sg] * HID + c;
        if (sg == 0 || sg == nSegR - 1) {
            if (v > 0.f) atomicMax((int*)dst, __float_as_int(v));
        } else {
            *dst = v;
        }
    }
}

// ---------------- node MLP + residual ----------------
__global__ __launch_bounds__(256, 4)
void node_mlp(const float* __restrict__ H,
              const unsigned short* __restrict__ Hb,
              const float* __restrict__ gmax,
              const float* __restrict__ W2,
              const unsigned short* __restrict__ W2t,
              float* __restrict__ out, int useAux) {
    __shared__ unsigned short sA[64][264];

    const int tid  = threadIdx.x;
    const int wave = tid >> 6;
    const int lane = tid & 63;
    const int base = blockIdx.x * 64;

    const int col = lane & 15;
    const int kr0 = (lane >> 4) * 8;
    bf16x8 bfrag[8][2];
    if (useAux) {
        #pragma unroll
        for (int ks = 0; ks < 8; ++ks)
            #pragma unroll
            for (int nf = 0; nf < 2; ++nf) {
                const int n = wave * 32 + nf * 16 + col;
                bfrag[ks][nf] = *(const bf16x8*)&W2t[(size_t)n * 256 + ks * 32 + kr0];
            }
    } else {
        #pragma unroll
        for (int ks = 0; ks < 8; ++ks)
            #pragma unroll
            for (int nf = 0; nf < 2; ++nf) {
                const int n  = wave * 32 + nf * 16 + col;
                const int kb = ks * 32 + kr0;
                bf16x8 b;
                #pragma unroll
                for (int f = 0; f < 8; ++f) b[f] = (short)f2bf(W2[(kb + f) * HID + n]);
                bfrag[ks][nf] = b;
            }
    }

    if (useAux) {
        #pragma unroll
        for (int it = 0; it < 4; ++it) {
            const int i   = tid + it * 256;
            const int row = i >> 4;
            const int c8  = (i & 15) * 8;
            int node = base + row;
            if (node >= N_NODES) node = N_NODES - 1;
            *(bf16x8*)&sA[row][c8] = *(const bf16x8*)(Hb + (size_t)node * D_H + c8);
        }
    } else {
        #pragma unroll
        for (int it = 0; it < 8; ++it) {
            const int i   = tid + it * 256;
            const int row = i >> 5;
            const int c4  = (i & 31) * 4;
            int node = base + row;
            if (node >= N_NODES) node = N_NODES - 1;
            *(s16x4*)&sA[row][c4] = pack4(*(const f32x4*)(H + (size_t)node * D_H + c4));
        }
    }
    #pragma unroll
    for (int it = 0; it < 8; ++it) {
        const int i   = tid + it * 256;
        const int row = i >> 5;
        const int c4  = (i & 31) * 4;
        int node = base + row;
        if (node >= N_NODES) node = N_NODES - 1;
        *(s16x4*)&sA[row][128 + c4] = pack4(*(const f32x4*)(gmax + (size_t)node * HID + c4));
    }
    __syncthreads();

    f32x4 acc[4][2];
    #pragma unroll
    for (int mm = 0; mm < 4; ++mm) {
        acc[mm][0] = f32x4{0.f, 0.f, 0.f, 0.f};
        acc[mm][1] = f32x4{0.f, 0.f, 0.f, 0.f};
    }
    const int arow = lane & 15;
    __builtin_amdgcn_s_setprio(1);
    #pragma unroll
    for (int ks = 0; ks < 8; ++ks)
        #pragma unroll
        for (int mm = 0; mm < 4; ++mm) {
            bf16x8 a = *(const bf16x8*)&sA[mm * 16 + arow][ks * 32 + kr0];
            acc[mm][0] = __builtin_amdgcn_mfma_f32_16x16x32_bf16(a, bfrag[ks][0], acc[mm][0], 0, 0, 0);
            acc[mm][1] = __builtin_amdgcn_mfma_f32_16x16x32_bf16(a, bfrag[ks][1], acc[mm][1], 0, 0, 0);
        }
    __builtin_amdgcn_s_setprio(0);

    const int rb = (lane >> 4) * 4;
    #pragma unroll
    for (int mm = 0; mm < 4; ++mm)
        #pragma unroll
        for (int r = 0; r < 4; ++r) {
            const int node = base + mm * 16 + rb + r;
            if (node < N_NODES) {
                const size_t o = (size_t)node * HID + wave * 32 + col;
                out[o]      = fmaxf(acc[mm][0][r], 0.f) + H[o];
                out[o + 16] = fmaxf(acc[mm][1][r], 0.f) + H[o + 16];
            }
        }
}

extern "C" void kernel_launch(void* const* d_in, const int* in_sizes, int n_in,
                              void* d_out, int out_size, void* d_ws, size_t ws_size,
                              hipStream_t stream) {
    const float* H   = (const float*)d_in[0];
    const int*   idx = (const int*)d_in[1];
    const float* Xe  = (const float*)d_in[2];
    const float* W1  = (const float*)d_in[3];
    const float* W2  = (const float*)d_in[4];
    float* out = (float*)d_out;

    // ---- workspace layout (core 32.4 MB; aux tail -> 45.3 MB)
    char* ws = (char*)d_ws;
    float* gmax   = (float*)(ws);                            // 25,600,000
    int*   deg    = (int*)(ws + 25600000);                   // 200,000 (scan_c -> cursor)
    int*   sc     = (int*)(ws + 25800192);                   // 200,000
    int*   totals = (int*)(ws + 26000384);                   // 512
    unsigned long long* pk8 = (unsigned long long*)(ws + 26000896); // 6,400,000
    unsigned short* W1t = (unsigned short*)(ws + 32400896);  // 49,152
    unsigned short* W2t = (unsigned short*)(ws + 32450048);  // 65,536
    unsigned short* Hb  = (unsigned short*)(ws + 32515584);  // 12,800,000
    const int useAux = (ws_size >= (size_t)45315584) ? 1 : 0;

    zero_ws<<<(NG4 + ND4 + 255) / 256, 256, 0, stream>>>(gmax, deg);
    if (useAux) {
        conv_hist<<<CB + HB, 256, 0, stream>>>(H, W1, W2, Hb, W1t, W2t, idx, deg, CB);
    } else {
        hist<<<HB, 256, 0, stream>>>(idx, deg);
    }
    scan_a<<<N_CHUNKS, SCAN_B, 0, stream>>>(deg, sc, totals);
    scan_b<<<1, 128, 0, stream>>>(totals);
    scan_c<<<N_CHUNKS, SCAN_B, 0, stream>>>(sc, totals, deg);
    scatter<<<(N_EDGES / 4 + 255) / 256, 256, 0, stream>>>(idx, deg, pk8);
    edge_sorted<<<N_ETILES, 256, 0, stream>>>(H, Hb, Xe, W1, W1t, pk8, gmax, useAux);
    node_mlp<<<(N_NODES + 63) / 64, 256, 0, stream>>>(H, Hb, gmax, W2, W2t, out, useAux);
}

// Round 19
// 231.296 us; speedup vs baseline: 1.0103x; 1.0103x over previous
//
#include <hip/hip_runtime.h>
#include <hip/hip_bf16.h>
#include <stdint.h>

#define N_NODES 50000
#define N_EDGES 800000
#define D_H 128
#define D_E 64
#define HID 128

#define MTILE 96
#define SMAX 16
#define N_ETILES ((N_EDGES + MTILE - 1) / MTILE)     // 8334

#define SCAN_B 512
#define N_CHUNKS ((N_NODES + SCAN_B - 1) / SCAN_B)   // 98

typedef __attribute__((ext_vector_type(8))) short bf16x8;
typedef __attribute__((ext_vector_type(4))) short s16x4;
typedef __attribute__((ext_vector_type(4))) float f32x4;
typedef __attribute__((ext_vector_type(4))) int i32x4;

__device__ __forceinline__ unsigned short f2bf(float x) {
    unsigned int u = __float_as_uint(x);
    u += 0x7FFFu + ((u >> 16) & 1u);   // round-to-nearest-even
    return (unsigned short)(u >> 16);
}

__device__ __forceinline__ s16x4 pack4(const f32x4 v) {
    s16x4 o = { (short)f2bf(v[0]), (short)f2bf(v[1]),
                (short)f2bf(v[2]), (short)f2bf(v[3]) };
    return o;
}

__device__ __forceinline__ bf16x8 pack8(const f32x4 a, const f32x4 b) {
    bf16x8 o = { (short)f2bf(a[0]), (short)f2bf(a[1]), (short)f2bf(a[2]), (short)f2bf(a[3]),
                 (short)f2bf(b[0]), (short)f2bf(b[1]), (short)f2bf(b[2]), (short)f2bf(b[3]) };
    return o;
}

// ---------------- fused prep: {gmax,deg} zero ++ {Hb,W1t,W2t} convert ----------------
#define NG4 (N_NODES * HID / 4)
#define ND4 (N_NODES / 4)
#define NHB4 (N_NODES * D_H / 4)
#define NW1 (192 * HID)
#define NW2 (256 * HID)
#define ZB  ((NG4 + ND4 + 255) / 256)
#define CB  ((NHB4 + NW1 + NW2 + 255) / 256)
__global__ void prep0(const float* __restrict__ H,
                      const float* __restrict__ W1,
                      const float* __restrict__ W2,
                      float* __restrict__ gmax, int* __restrict__ deg,
                      unsigned short* __restrict__ Hb,
                      unsigned short* __restrict__ W1t,
                      unsigned short* __restrict__ W2t) {
    const int b = blockIdx.x;
    if (b < ZB) {
        const int i = b * 256 + threadIdx.x;
        if (i < NG4) {
            ((f32x4*)gmax)[i] = f32x4{0.f, 0.f, 0.f, 0.f};
        } else if (i < NG4 + ND4) {
            ((i32x4*)deg)[i - NG4] = i32x4{0, 0, 0, 0};
        }
    } else {
        const int i = (b - ZB) * 256 + threadIdx.x;
        if (i < NHB4) {
            ((s16x4*)Hb)[i] = pack4(((const f32x4*)H)[i]);
        } else if (i < NHB4 + NW1) {                 // W1t [128][192] bf16
            const int j = i - NHB4;
            const int n = j / 192, k = j - n * 192;
            W1t[j] = f2bf(W1[k * HID + n]);
        } else if (i < NHB4 + NW1 + NW2) {           // W2t [128][256] bf16
            const int j = i - NHB4 - NW1;
            const int n = j >> 8, k = j & 255;
            W2t[j] = f2bf(W2[k * HID + n]);
        }
    }
}

// ---------------- histogram: 4 edges/thread ----------------
__global__ void hist(const int* __restrict__ idx, int* __restrict__ deg) {
    const int i = blockIdx.x * blockDim.x + threadIdx.x;
    if (i < N_EDGES / 4) {
        const i32x4 d4 = ((const i32x4*)(idx + N_EDGES))[i];
        atomicAdd(&deg[d4.x], 1);
        atomicAdd(&deg[d4.y], 1);
        atomicAdd(&deg[d4.z], 1);
        atomicAdd(&deg[d4.w], 1);
    }
}

// ---------------- 3-kernel parallel exclusive scan ----------------
__global__ void scan_a(const int* __restrict__ deg, int* __restrict__ sc,
                       int* __restrict__ totals) {
    __shared__ int s[SCAN_B];
    const int tid = threadIdx.x;
    const int i = blockIdx.x * SCAN_B + tid;
    const int v = (i < N_NODES) ? deg[i] : 0;
    s[tid] = v;
    __syncthreads();
    for (int o = 1; o < SCAN_B; o <<= 1) {
        int t = (tid >= o) ? s[tid - o] : 0;
        __syncthreads();
        s[tid] += t;
        __syncthreads();
    }
    if (i < N_NODES) sc[i] = s[tid] - v;
    if (tid == SCAN_B - 1) totals[blockIdx.x] = s[SCAN_B - 1];
}

__global__ void scan_b(int* __restrict__ totals) {
    __shared__ int s[128];
    const int tid = threadIdx.x;
    const int v = (tid < N_CHUNKS) ? totals[tid] : 0;
    s[tid] = v;
    __syncthreads();
    for (int o = 1; o < 128; o <<= 1) {
        int t = (tid >= o) ? s[tid - o] : 0;
        __syncthreads();
        s[tid] += t;
        __syncthreads();
    }
    if (tid < N_CHUNKS) totals[tid] = s[tid] - v;
}

__global__ void scan_c(const int* __restrict__ sc, const int* __restrict__ totals,
                       int* __restrict__ cursor) {
    const int i = blockIdx.x * SCAN_B + threadIdx.x;
    if (i < N_NODES) cursor[i] = sc[i] + totals[blockIdx.x];
}

// ---------------- scatter: 4 edges/thread, packed 8B store per edge ----------------
__global__ void scatter(const int* __restrict__ idx, int* __restrict__ cursor,
                        unsigned long long* __restrict__ pk8) {
    const int i = blockIdx.x * blockDim.x + threadIdx.x;
    if (i < N_EDGES / 4) {
        const i32x4 s4 = ((const i32x4*)idx)[i];
        const i32x4 d4 = ((const i32x4*)(idx + N_EDGES))[i];
        #pragma unroll
        for (int q = 0; q < 4; ++q) {
            const int e = i * 4 + q;
            const int s = (q == 0) ? s4.x : (q == 1) ? s4.y : (q == 2) ? s4.z : s4.w;
            const int d = (q == 0) ? d4.x : (q == 1) ? d4.y : (q == 2) ? d4.z : d4.w;
            const int p = atomicAdd(&cursor[d], 1);
            pk8[p] = (unsigned long long)(unsigned)e |
                     ((unsigned long long)(unsigned)s << 20) |
                     ((unsigned long long)(unsigned)d << 37);
        }
    }
}

// ---------------- edge MLP: gld_lds H-staging, ymax ALIASED onto sH ----------------
// LDS ~39 KB -> 4 blocks/CU. ymax reuses sH after MFMA (B2/B3 barriers separate
// liveness). Swizzle per rule #21: source-side XOR, linear LDS dest, XOR on read.
__global__ __launch_bounds__(256, 4)
void edge_sorted(const float* __restrict__ H,
                 const unsigned short* __restrict__ Hb,
                 const float* __restrict__ Xe,
                 const float* __restrict__ W1,
                 const unsigned short* __restrict__ W1t,
                 const unsigned long long* __restrict__ pk8,
                 float* __restrict__ gmax, int useAux) {
    __shared__ unsigned short sH[MTILE * 128];       // 24.6 KB; ymax aliases this
    __shared__ unsigned short sXe[MTILE][72];        // 13.8 KB (64 + 8 pad)
    __shared__ int rowD[MTILE];
    __shared__ int segNode[SMAX];
    __shared__ int sWaveTot[4];
    __shared__ unsigned char rowG[MTILE];

    float (*ymax)[132] = reinterpret_cast<float(*)[132]>(sH);   // 8.4 KB < 24.6 KB

    const int tid  = threadIdx.x;
    const int wave = tid >> 6;
    const int lane = tid & 63;
    const int p0   = blockIdx.x * MTILE;

    const int col = lane & 15;
    const int kr0 = (lane >> 4) * 8;

    // --- stage H: async DMA to LDS (useAux) or register path (fallback) ---
    if (useAux) {
        #pragma unroll
        for (int it = 0; it < 6; ++it) {
            const int j   = tid + it * 256;          // < 1536 = 96 rows x 16 chunks
            const int row = j >> 4;
            const int ch  = j & 15;
            int pe = p0 + row; if (pe >= N_EDGES) pe = N_EDGES - 1;
            const int src = (int)((pk8[pe] >> 20) & 0x1FFFFull);
            const int sw  = ch ^ (row & 7);          // source-side swizzle
            unsigned short* lbase = sH + (size_t)(it * 256 + wave * 64) * 8;
            __builtin_amdgcn_global_load_lds(
                (const __attribute__((address_space(1))) void*)(Hb + (size_t)src * D_H + sw * 8),
                (__attribute__((address_space(3))) void*)lbase,
                16, 0, 0);
        }
    } else {
        #pragma unroll
        for (int it = 0; it < 12; ++it) {
            const int j   = tid + it * 256;          // < 3072
            const int row = j >> 5;
            const int q4  = j & 31;
            const int c   = q4 >> 1;
            const int hl  = q4 & 1;
            int pe = p0 + row; if (pe >= N_EDGES) pe = N_EDGES - 1;
            const int src = (int)((pk8[pe] >> 20) & 0x1FFFFull);
            const f32x4 v = *(const f32x4*)(H + (size_t)src * D_H + q4 * 4);
            const int sw  = c ^ (row & 7);
            *(s16x4*)&sH[(size_t)row * 128 + sw * 8 + hl * 4] = pack4(v);
        }
    }
    // --- stage Xe (register path: needs f32->bf16 convert) ---
    #pragma unroll
    for (int it = 0; it < 3; ++it) {
        const int j   = tid + it * 256;              // < 768
        const int row = j >> 3;
        const int c8  = (j & 7) * 8;
        int pe = p0 + row; if (pe >= N_EDGES) pe = N_EDGES - 1;
        const int e = (int)(pk8[pe] & 0xFFFFFull);
        const float* p = Xe + (size_t)e * D_E + c8;
        *(bf16x8*)&sXe[row][c8] = pack8(*(const f32x4*)p, *(const f32x4*)(p + 4));
    }

    // --- B fragments (W1), wave covers cols [wave*32, wave*32+32)
    bf16x8 bfrag[6][2];
    if (useAux) {
        #pragma unroll
        for (int ks = 0; ks < 6; ++ks)
            #pragma unroll
            for (int nf = 0; nf < 2; ++nf) {
                const int n = wave * 32 + nf * 16 + col;
                bfrag[ks][nf] = *(const bf16x8*)&W1t[(size_t)n * 192 + ks * 32 + kr0];
            }
    } else {
        #pragma unroll
        for (int ks = 0; ks < 6; ++ks)
            #pragma unroll
            for (int nf = 0; nf < 2; ++nf) {
                const int n  = wave * 32 + nf * 16 + col;
                const int kb = ks * 32 + kr0;
                bf16x8 b;
                #pragma unroll
                for (int f = 0; f < 8; ++f) b[f] = (short)f2bf(W1[(kb + f) * HID + n]);
                bfrag[ks][nf] = b;
            }
    }

    // --- tile-local segmentation ---
    const int pe0 = p0 + tid;
    const bool inTile = (tid < MTILE);
    const bool valid  = inTile && (pe0 < N_EDGES);
    int d = 0;
    if (inTile) {
        const int pc = valid ? pe0 : (N_EDGES - 1);
        d = (int)(pk8[pc] >> 37);
        rowD[tid] = d;
    }
    int dp = __shfl_up(d, 1);
    if (lane == 0 && inTile && tid > 0) dp = (int)(pk8[pe0 - 1] >> 37);
    const bool flag = valid && (tid == 0 || d != dp);
    const unsigned long long m = __ballot(flag);
    if (lane == 0) sWaveTot[wave] = (int)__popcll(m);
    __syncthreads();                                  // A: gld_lds drained, sWaveTot ready

    const int nSegR = sWaveTot[0] + sWaveTot[1];      // capture in register
    int g = 255;
    if (valid) {
        const unsigned long long le =
            (lane == 63) ? ~0ull : ((1ull << (lane + 1)) - 1);
        g = (int)__popcll(m & le) - 1 + ((wave == 1) ? sWaveTot[0] : 0);
    }
    if (inTile) rowG[tid] = (unsigned char)(valid ? g : 255);
    if (flag && g < SMAX) segNode[g] = d;
    __syncthreads();                                  // B: sH/sXe + rowG + segNode ready

    // --- MFMA: 96 x 192 @ 192 x 32 per wave (swizzled sH read for ks<4)
    f32x4 acc[6][2];
    #pragma unroll
    for (int mm = 0; mm < 6; ++mm) {
        acc[mm][0] = f32x4{0.f, 0.f, 0.f, 0.f};
        acc[mm][1] = f32x4{0.f, 0.f, 0.f, 0.f};
    }
    const int arow = lane & 15;
    const int cgrp = lane >> 4;
    __builtin_amdgcn_s_setprio(1);
    #pragma unroll
    for (int ks = 0; ks < 6; ++ks)
        #pragma unroll
        for (int mm = 0; mm < 6; ++mm) {
            const int r = mm * 16 + arow;
            bf16x8 a;
            if (ks < 4) {
                const int c = ks * 4 + cgrp;
                a = *(const bf16x8*)&sH[(size_t)r * 128 + ((c ^ (r & 7)) << 3)];
            } else {
                a = *(const bf16x8*)&sXe[r][(ks - 4) * 32 + kr0];
            }
            acc[mm][0] = __builtin_amdgcn_mfma_f32_16x16x32_bf16(a, bfrag[ks][0], acc[mm][0], 0, 0, 0);
            acc[mm][1] = __builtin_amdgcn_mfma_f32_16x16x32_bf16(a, bfrag[ks][1], acc[mm][1], 0, 0, 0);
        }
    __builtin_amdgcn_s_setprio(0);
    __syncthreads();                                  // B2: all sH reads done -> sH dead

    // --- zero the aliased ymax region ---
    for (int i2 = tid; i2 < SMAX * 132; i2 += 256) ((float*)ymax)[i2] = 0.f;
    __syncthreads();                                  // B3: zeros visible

    // --- relu + segmented max into LDS (overflow segs -> direct global atomics)
    const int rb = (lane >> 4) * 4;
    const int cb = wave * 32 + col;
    #pragma unroll
    for (int mm = 0; mm < 6; ++mm) {
        const int r0 = mm * 16 + rb;
        const int g0 = rowG[r0];
        const int g3 = rowG[r0 + 3];
        if (g0 == g3) {
            const float v0 = fmaxf(fmaxf(acc[mm][0][0], acc[mm][0][1]),
                                   fmaxf(acc[mm][0][2], acc[mm][0][3]));
            const float v1 = fmaxf(fmaxf(acc[mm][1][0], acc[mm][1][1]),
                                   fmaxf(acc[mm][1][2], acc[mm][1][3]));
            if (g0 < SMAX) {
                if (v0 > 0.f) atomicMax((int*)&ymax[g0][cb],      __float_as_int(v0));
                if (v1 > 0.f) atomicMax((int*)&ymax[g0][cb + 16], __float_as_int(v1));
            } else if (g0 < 255) {
                float* base = gmax + (size_t)rowD[r0] * HID;
                if (v0 > 0.f) atomicMax((int*)(base + cb),      __float_as_int(v0));
                if (v1 > 0.f) atomicMax((int*)(base + cb + 16), __float_as_int(v1));
            }
        } else {
            #pragma unroll
            for (int r = 0; r < 4; ++r) {
                const int gg = rowG[r0 + r];
                const float v0 = acc[mm][0][r];
                const float v1 = acc[mm][1][r];
                if (gg < SMAX) {
                    if (v0 > 0.f) atomicMax((int*)&ymax[gg][cb],      __float_as_int(v0));
                    if (v1 > 0.f) atomicMax((int*)&ymax[gg][cb + 16], __float_as_int(v1));
                } else if (gg < 255) {
                    float* base = gmax + (size_t)rowD[r0 + r] * HID;
                    if (v0 > 0.f) atomicMax((int*)(base + cb),      __float_as_int(v0));
                    if (v1 > 0.f) atomicMax((int*)(base + cb + 16), __float_as_int(v1));
                }
            }
        }
    }
    __syncthreads();                                  // C: ymax complete

    // --- writeout: interior segments plain store, first/last atomicMax
    const int nS = (nSegR < SMAX) ? nSegR : SMAX;
    for (int i2 = tid; i2 < nS * 128; i2 += 256) {
        const int sg = i2 >> 7;
        const int c  = i2 & 127;
        const float v = ymax[sg][c];
        float* dst = gmax + (size_t)segNode[sg] * HID + c;
        if (sg == 0 || sg == nSegR - 1) {
            if (v > 0.f) atomicMax((int*)dst, __float_as_int(v));
        } else {
            *dst = v;
        }
    }
}

// ---------------- node MLP + residual ----------------
__global__ __launch_bounds__(256, 4)
void node_mlp(const float* __restrict__ H,
              const unsigned short* __restrict__ Hb,
              const float* __restrict__ gmax,
              const float* __restrict__ W2,
              const unsigned short* __restrict__ W2t,
              float* __restrict__ out, int useAux) {
    __shared__ unsigned short sA[64][264];

    const int tid  = threadIdx.x;
    const int wave = tid >> 6;
    const int lane = tid & 63;
    const int base = blockIdx.x * 64;

    const int col = lane & 15;
    const int kr0 = (lane >> 4) * 8;
    bf16x8 bfrag[8][2];
    if (useAux) {
        #pragma unroll
        for (int ks = 0; ks < 8; ++ks)
            #pragma unroll
            for (int nf = 0; nf < 2; ++nf) {
                const int n = wave * 32 + nf * 16 + col;
                bfrag[ks][nf] = *(const bf16x8*)&W2t[(size_t)n * 256 + ks * 32 + kr0];
            }
    } else {
        #pragma unroll
        for (int ks = 0; ks < 8; ++ks)
            #pragma unroll
            for (int nf = 0; nf < 2; ++nf) {
                const int n  = wave * 32 + nf * 16 + col;
                const int kb = ks * 32 + kr0;
                bf16x8 b;
                #pragma unroll
                for (int f = 0; f < 8; ++f) b[f] = (short)f2bf(W2[(kb + f) * HID + n]);
                bfrag[ks][nf] = b;
            }
    }

    if (useAux) {
        #pragma unroll
        for (int it = 0; it < 4; ++it) {
            const int i   = tid + it * 256;          // < 1024 = 64 rows x 16 granules
            const int row = i >> 4;
            const int c8  = (i & 15) * 8;
            int node = base + row;
            if (node >= N_NODES) node = N_NODES - 1;
            *(bf16x8*)&sA[row][c8] = *(const bf16x8*)(Hb + (size_t)node * D_H + c8);
        }
    } else {
        #pragma unroll
        for (int it = 0; it < 8; ++it) {
            const int i   = tid + it * 256;
            const int row = i >> 5;
            const int c4  = (i & 31) * 4;
            int node = base + row;
            if (node >= N_NODES) node = N_NODES - 1;
            *(s16x4*)&sA[row][c4] = pack4(*(const f32x4*)(H + (size_t)node * D_H + c4));
        }
    }
    #pragma unroll
    for (int it = 0; it < 8; ++it) {
        const int i   = tid + it * 256;
        const int row = i >> 5;
        const int c4  = (i & 31) * 4;
        int node = base + row;
        if (node >= N_NODES) node = N_NODES - 1;
        *(s16x4*)&sA[row][128 + c4] = pack4(*(const f32x4*)(gmax + (size_t)node * HID + c4));
    }
    __syncthreads();

    f32x4 acc[4][2];
    #pragma unroll
    for (int mm = 0; mm < 4; ++mm) {
        acc[mm][0] = f32x4{0.f, 0.f, 0.f, 0.f};
        acc[mm][1] = f32x4{0.f, 0.f, 0.f, 0.f};
    }
    const int arow = lane & 15;
    __builtin_amdgcn_s_setprio(1);
    #pragma unroll
    for (int ks = 0; ks < 8; ++ks)
        #pragma unroll
        for (int mm = 0; mm < 4; ++mm) {
            bf16x8 a = *(const bf16x8*)&sA[mm * 16 + arow][ks * 32 + kr0];
            acc[mm][0] = __builtin_amdgcn_mfma_f32_16x16x32_bf16(a, bfrag[ks][0], acc[mm][0], 0, 0, 0);
            acc[mm][1] = __builtin_amdgcn_mfma_f32_16x16x32_bf16(a, bfrag[ks][1], acc[mm][1], 0, 0, 0);
        }
    __builtin_amdgcn_s_setprio(0);

    const int rb = (lane >> 4) * 4;
    #pragma unroll
    for (int mm = 0; mm < 4; ++mm)
        #pragma unroll
        for (int r = 0; r < 4; ++r) {
            const int node = base + mm * 16 + rb + r;
            if (node < N_NODES) {
                const size_t o = (size_t)node * HID + wave * 32 + col;
                out[o]      = fmaxf(acc[mm][0][r], 0.f) + H[o];
                out[o + 16] = fmaxf(acc[mm][1][r], 0.f) + H[o + 16];
            }
        }
}

extern "C" void kernel_launch(void* const* d_in, const int* in_sizes, int n_in,
                              void* d_out, int out_size, void* d_ws, size_t ws_size,
                              hipStream_t stream) {
    const float* H   = (const float*)d_in[0];
    const int*   idx = (const int*)d_in[1];
    const float* Xe  = (const float*)d_in[2];
    const float* W1  = (const float*)d_in[3];
    const float* W2  = (const float*)d_in[4];
    float* out = (float*)d_out;

    // ---- workspace layout (core 32.4 MB; aux tail -> 45.3 MB)
    char* ws = (char*)d_ws;
    float* gmax   = (float*)(ws);                            // 25,600,000
    int*   deg    = (int*)(ws + 25600000);                   // 200,000 (scan_c -> cursor)
    int*   sc     = (int*)(ws + 25800192);                   // 200,000
    int*   totals = (int*)(ws + 26000384);                   // 512
    unsigned long long* pk8 = (unsigned long long*)(ws + 26000896); // 6,400,000
    unsigned short* W1t = (unsigned short*)(ws + 32400896);  // 49,152
    unsigned short* W2t = (unsigned short*)(ws + 32450048);  // 65,536
    unsigned short* Hb  = (unsigned short*)(ws + 32515584);  // 12,800,000
    const int useAux = (ws_size >= (size_t)45315584) ? 1 : 0;

    const int nPrep = ZB + (useAux ? CB : 0);
    prep0<<<nPrep, 256, 0, stream>>>(H, W1, W2, gmax, deg, Hb, W1t, W2t);
    hist<<<(N_EDGES / 4 + 255) / 256, 256, 0, stream>>>(idx, deg);
    scan_a<<<N_CHUNKS, SCAN_B, 0, stream>>>(deg, sc, totals);
    scan_b<<<1, 128, 0, stream>>>(totals);
    scan_c<<<N_CHUNKS, SCAN_B, 0, stream>>>(sc, totals, deg);
    scatter<<<(N_EDGES / 4 + 255) / 256, 256, 0, stream>>>(idx, deg, pk8);
    edge_sorted<<<N_ETILES, 256, 0, stream>>>(H, Hb, Xe, W1, W1t, pk8, gmax, useAux);
    node_mlp<<<(N_NODES + 63) / 64, 256, 0, stream>>>(H, Hb, gmax, W2, W2t, out, useAux);
}